// Round 1
// baseline (261.519 us; speedup 1.0000x reference)
//
#include <hip/hip_runtime.h>

// CrossWarpingModule: 4-phase pixel-unshuffle -> axial attention (8 heads, c=1)
// -> flow -> bilinear border grid_sample -> pixel-shuffle back.
// B=2, C=64, H=W=256; sub-images: 8 x [64][128][128].
//
// Key algebra: per-head channel dim is 1, so q,k,v are 8 scalars/pixel.
// grid_sample coords: ix = w + o_hor, iy = h + o_ver (normalization cancels).

constexpr int PLANE = 128 * 128;            // 16384 = 1<<14
constexpr float LOG2E = 1.4426950408889634f;

// phase p -> (dy,dx): p0=(0,0) p1=(1,1) p2=(0,1) p3=(1,0)
__device__ __forceinline__ int phase_dy(int p) { return p & 1; }
__device__ __forceinline__ int phase_dx(int p) { return (p == 1) | (p == 2); }

// ---------------------------------------------------------------------------
// Kernel 1: q/k/v projection. One thread per sub-pixel (131072 total).
// Writes Q,K,V in [sb][head][h][w] and QT,KT,VT in [sb][head][w][h].
// ---------------------------------------------------------------------------
__global__ __launch_bounds__(256) void qkv_kernel(
    const float* __restrict__ cur, const float* __restrict__ ref,
    const float* __restrict__ Wq, const float* __restrict__ Wk,
    const float* __restrict__ Wv,
    float* __restrict__ Q, float* __restrict__ K, float* __restrict__ V,
    float* __restrict__ QT, float* __restrict__ KT, float* __restrict__ VT)
{
    // WT[c][j]: j in [0,8)=Wq row j col c, [8,16)=Wk, [16,24)=Wv.
    __shared__ __align__(16) float WT[64 * 24];
    const int tid = threadIdx.x;
    for (int i = tid; i < 64 * 24; i += 256) {
        int c = i / 24, j = i % 24;
        float val;
        if (j < 8)       val = Wq[j * 64 + c];
        else if (j < 16) val = Wk[(j - 8) * 64 + c];
        else             val = Wv[(j - 16) * 64 + c];
        WT[c * 24 + j] = val;
    }
    __syncthreads();

    const int idx = blockIdx.x * 256 + tid;   // [0, 131072)
    const int sb  = idx >> 14;                // sub-image 0..7
    const int pix = idx & (PLANE - 1);
    const int h = pix >> 7, w = pix & 127;
    const int p = sb >> 1, b = sb & 1;
    const int Y = 2 * h + phase_dy(p), X = 2 * w + phase_dx(p);

    const int base_in = b * 64 * 65536 + Y * 256 + X;
    const float* curp = cur + base_in;
    const float* refp = ref + base_in;

    float q[8], k[8], v[8];
#pragma unroll
    for (int i = 0; i < 8; ++i) { q[i] = 0.f; k[i] = 0.f; v[i] = 0.f; }

#pragma unroll 4
    for (int c = 0; c < 64; ++c) {
        float cu = curp[c * 65536];
        float rf = refp[c * 65536];
        const float* wr = &WT[c * 24];
#pragma unroll
        for (int i = 0; i < 8; ++i) {
            q[i] = fmaf(wr[i],      cu, q[i]);
            k[i] = fmaf(wr[8 + i],  rf, k[i]);
            v[i] = fmaf(wr[16 + i], rf, v[i]);
        }
    }

#pragma unroll
    for (int i = 0; i < 8; ++i) {
        const int base = (sb * 8 + i) << 14;
        const int nrm = base + (h << 7) + w;   // [head][h][w] (coalesced)
        const int trn = base + (w << 7) + h;   // [head][w][h] (scattered)
        Q[nrm] = q[i];  K[nrm] = k[i];  V[nrm] = v[i];
        QT[trn] = q[i]; KT[trn] = k[i]; VT[trn] = v[i];
    }
}

// ---------------------------------------------------------------------------
// Kernel 2: axial attention + 8->1 output projection.
// TRANS=1: vertical (inputs are *T arrays; block = (sb, column w), t = h;
//          output scattered back to [sb][h][w]).
// TRANS=0: horizontal (block = (sb, row h), t = w; all coalesced).
// softmax over the 128 staged elements, no max-subtract (|q*k| << 88).
// ---------------------------------------------------------------------------
template <int TRANS>
__global__ __launch_bounds__(128) void attn_kernel(
    const float* __restrict__ Qa, const float* __restrict__ Ka,
    const float* __restrict__ Va, const float* __restrict__ wsel,
    float* __restrict__ o)
{
    __shared__ __align__(16) float kk[8 * 132];  // pre-scaled by log2(e)
    __shared__ __align__(16) float vv[8 * 132];  // stride 132: 16B-aligned rows

    const int t   = threadIdx.x;       // 0..127
    const int blk = blockIdx.x;        // 0..1023
    const int sb  = blk >> 7;
    const int fix = blk & 127;         // the fixed (column|row) index

    float qv[8];
#pragma unroll
    for (int head = 0; head < 8; ++head) {
        const int base = ((sb * 8 + head) << 14) + (fix << 7);
        kk[head * 132 + t] = LOG2E * Ka[base + t];
        vv[head * 132 + t] = Va[base + t];
        qv[head] = Qa[base + t];
    }
    float w8[8];
#pragma unroll
    for (int head = 0; head < 8; ++head) w8[head] = wsel[head];
    __syncthreads();

    float acc = 0.f;
    for (int head = 0; head < 8; ++head) {
        const float s = qv[head];
        const float4* k4 = (const float4*)&kk[head * 132];
        const float4* v4 = (const float4*)&vv[head * 132];
        float num = 0.f, den = 0.f;
#pragma unroll 4
        for (int l = 0; l < 32; ++l) {
            float4 kq = k4[l];
            float4 vq = v4[l];
            float e0 = exp2f(s * kq.x); den += e0; num = fmaf(e0, vq.x, num);
            float e1 = exp2f(s * kq.y); den += e1; num = fmaf(e1, vq.y, num);
            float e2 = exp2f(s * kq.z); den += e2; num = fmaf(e2, vq.z, num);
            float e3 = exp2f(s * kq.w); den += e3; num = fmaf(e3, vq.w, num);
        }
        acc = fmaf(w8[head], num / den, acc);
    }

    if (TRANS) o[(sb << 14) + (t << 7) + fix] = acc;  // o_ver[sb][h=t][w=fix]
    else       o[(sb << 14) + (fix << 7) + t] = acc;  // o_hor[sb][h=fix][w=t]
}

// ---------------------------------------------------------------------------
// Kernel 3: bilinear border-clamped sample of ref_sub (read straight from
// ref_fea via phase mapping) + scatter into interleaved output.
// ---------------------------------------------------------------------------
__global__ __launch_bounds__(256) void warp_kernel(
    const float* __restrict__ ref, const float* __restrict__ ov,
    const float* __restrict__ oh, float* __restrict__ out)
{
    const int idx = blockIdx.x * 256 + threadIdx.x;  // [0, 131072)
    const int sb  = idx >> 14;
    const int pix = idx & (PLANE - 1);
    const int h = pix >> 7, w = pix & 127;
    const int p = sb >> 1, b = sb & 1;
    const int dy = phase_dy(p), dx = phase_dx(p);

    // normalized-coord round trip cancels exactly:
    const float ix = (float)w + oh[idx];
    const float iy = (float)h + ov[idx];

    const float x0f = floorf(ix), y0f = floorf(iy);
    const float wx = ix - x0f,    wy = iy - y0f;
    const int x0 = (int)x0f, y0 = (int)y0f;
    const int x0c = min(max(x0, 0), 127),     x1c = min(max(x0 + 1, 0), 127);
    const int y0c = min(max(y0, 0), 127),     y1c = min(max(y0 + 1, 0), 127);

    const float w00 = (1.f - wx) * (1.f - wy);
    const float w01 = wx * (1.f - wy);
    const float w10 = (1.f - wx) * wy;
    const float w11 = wx * wy;

    const int r0 = (2 * y0c + dy) * 256, r1 = (2 * y1c + dy) * 256;
    const int c0 = 2 * x0c + dx,         c1 = 2 * x1c + dx;
    const int o00 = r0 + c0, o01 = r0 + c1, o10 = r1 + c0, o11 = r1 + c1;
    const int dst = (2 * h + dy) * 256 + (2 * w + dx);

    const float* rp = ref + b * 64 * 65536;
    float* op = out + b * 64 * 65536;

#pragma unroll 4
    for (int c = 0; c < 64; ++c) {
        const int pl = c * 65536;
        const float v00 = rp[pl + o00], v01 = rp[pl + o01];
        const float v10 = rp[pl + o10], v11 = rp[pl + o11];
        op[pl + dst] = fmaf(w00, v00, fmaf(w01, v01, fmaf(w10, v10, w11 * v11)));
    }
}

// ---------------------------------------------------------------------------
extern "C" void kernel_launch(void* const* d_in, const int* in_sizes, int n_in,
                              void* d_out, int out_size, void* d_ws, size_t ws_size,
                              hipStream_t stream)
{
    const float* cur  = (const float*)d_in[0];
    const float* ref  = (const float*)d_in[1];
    const float* Wq   = (const float*)d_in[2];
    const float* Wk   = (const float*)d_in[3];
    const float* Wv   = (const float*)d_in[4];
    const float* Wver = (const float*)d_in[5];
    const float* Whor = (const float*)d_in[6];
    float* out = (float*)d_out;

    float* ws = (float*)d_ws;
    const size_t NQ = 8 * 8 * (size_t)PLANE;  // 1,048,576 floats per array
    float* Q  = ws;       float* K  = Q  + NQ; float* V  = K  + NQ;
    float* QT = V  + NQ;  float* KT = QT + NQ; float* VT = KT + NQ;
    float* OV = VT + NQ;                       // [8][128][128]
    float* OH = OV + 8 * (size_t)PLANE;

    qkv_kernel<<<512, 256, 0, stream>>>(cur, ref, Wq, Wk, Wv,
                                        Q, K, V, QT, KT, VT);
    attn_kernel<1><<<1024, 128, 0, stream>>>(QT, KT, VT, Wver, OV); // vertical
    attn_kernel<0><<<1024, 128, 0, stream>>>(Q,  K,  V,  Whor, OH); // horizontal
    warp_kernel<<<512, 256, 0, stream>>>(ref, OV, OH, out);
}

// Round 2
// 237.062 us; speedup vs baseline: 1.1032x; 1.1032x over previous
//
#include <hip/hip_runtime.h>

// CrossWarpingModule: 4-phase pixel-unshuffle -> axial attention (8 heads, c=1)
// -> flow -> bilinear border grid_sample -> pixel-shuffle back.
// B=2, C=64, H=W=256; sub-images: 8 x [64][128][128].
//
// R2 structure:
//   qkv:       coalesced X-contiguous reads, 2-way channel split, Q/K/V normal only
//   transpose: KT,VT via 32x32 LDS tiles (coalesced both sides)
//   attn_axial<VER>: wave-uniform k/v line read via scalar pipe (no LDS),
//                    inner loop = mul+exp2+2fma; VER writes OVT coalesced
//   warp:      bilinear border gather, 2-way channel split

constexpr int PLANE = 16384;                 // 128*128
constexpr float LOG2E = 1.4426950408889634f;

// ---------------------------------------------------------------------------
// Kernel 1: q/k/v projection. Block = (b, Y, X-half): 128 contiguous X
// positions x 2 channel-groups. Reads stride-1 coalesced. grid 1024 x 256.
// ---------------------------------------------------------------------------
__global__ __launch_bounds__(256) void qkv_kernel(
    const float* __restrict__ cur, const float* __restrict__ ref,
    const float* __restrict__ Wq, const float* __restrict__ Wk,
    const float* __restrict__ Wv,
    float* __restrict__ Q, float* __restrict__ K, float* __restrict__ V)
{
    __shared__ float WT[64 * 24];     // WT[c][j]: j<8 Wq, <16 Wk, <24 Wv
    __shared__ float red[128 * 25];   // pad 25: conflict-free reduce
    const int tid = threadIdx.x;
    for (int i = tid; i < 64 * 24; i += 256) {
        int c = i / 24, j = i % 24;
        float val = (j < 8) ? Wq[j * 64 + c]
                  : (j < 16) ? Wk[(j - 8) * 64 + c]
                  : Wv[(j - 16) * 64 + c];
        WT[c * 24 + j] = val;
    }
    __syncthreads();

    const int bi = blockIdx.x;               // 0..1023
    const int b  = bi >> 9;                  // batch
    const int Y  = (bi >> 1) & 255;          // full-res row
    const int Xh = bi & 1;                   // X half
    const int cg = tid >> 7;                 // channel group 0/1
    const int xi = tid & 127;
    const int X  = Xh * 128 + xi;            // full-res col (contiguous per lane)

    const size_t base_in = (size_t)b * 64 * 65536 + (size_t)Y * 256 + X;
    const float* curp = cur + base_in;
    const float* refp = ref + base_in;

    float q[8], k[8], v[8];
#pragma unroll
    for (int i = 0; i < 8; ++i) { q[i] = 0.f; k[i] = 0.f; v[i] = 0.f; }

    const int c0 = cg * 32;
#pragma unroll 4
    for (int c = 0; c < 32; ++c) {
        float cu = curp[(size_t)(c0 + c) * 65536];
        float rf = refp[(size_t)(c0 + c) * 65536];
        const float* wr = &WT[(c0 + c) * 24];
#pragma unroll
        for (int i = 0; i < 8; ++i) {
            q[i] = fmaf(wr[i],      cu, q[i]);
            k[i] = fmaf(wr[8 + i],  rf, k[i]);
            v[i] = fmaf(wr[16 + i], rf, v[i]);
        }
    }

    if (cg) {
#pragma unroll
        for (int i = 0; i < 8; ++i) {
            red[xi * 25 + i]      = q[i];
            red[xi * 25 + 8 + i]  = k[i];
            red[xi * 25 + 16 + i] = v[i];
        }
    }
    __syncthreads();
    if (!cg) {
        const int dy = Y & 1, dx = X & 1;
        // (dy,dx)->phase: (0,0)=0 (1,1)=1 (0,1)=2 (1,0)=3
        const int p  = dy ? (dx ? 1 : 3) : (dx ? 2 : 0);
        const int sb = p * 2 + b;
        const int h = Y >> 1, w = X >> 1;
#pragma unroll
        for (int i = 0; i < 8; ++i) {
            const size_t o = ((size_t)(sb * 8 + i) << 14) + (h << 7) + w;
            Q[o] = q[i] + red[xi * 25 + i];
            K[o] = k[i] + red[xi * 25 + 8 + i];
            V[o] = v[i] + red[xi * 25 + 16 + i];
        }
    }
}

// ---------------------------------------------------------------------------
// Kernel 2: per-plane 128x128 transpose of K,V -> KT,VT. 32x32 LDS tiles,
// coalesced float4 on both sides. grid 1024 x 256.
// ---------------------------------------------------------------------------
__global__ __launch_bounds__(256) void transpose_kernel(
    const float* __restrict__ K, const float* __restrict__ V,
    float* __restrict__ KT, float* __restrict__ VT)
{
    __shared__ float tile[32 * 33];
    const int bi = blockIdx.x;         // 0..1023
    const int plane = bi >> 4;         // (sb*8+head)
    const int ti = (bi >> 2) & 3, tj = bi & 3;
    const int t = threadIdx.x;
    const int r = t >> 3, c4 = (t & 7) * 4;     // 32 rows x 8 float4 cols
    const size_t pb = (size_t)plane << 14;
    const size_t ibase = pb + (size_t)(ti * 32) * 128 + tj * 32;
    const size_t obase = pb + (size_t)(tj * 32) * 128 + ti * 32;

#pragma unroll
    for (int a = 0; a < 2; ++a) {
        const float* src = a ? V : K;
        float* dst = a ? VT : KT;
        const float4 val = *(const float4*)&src[ibase + (size_t)r * 128 + c4];
        if (a) __syncthreads();
        tile[r * 33 + c4 + 0] = val.x;
        tile[r * 33 + c4 + 1] = val.y;
        tile[r * 33 + c4 + 2] = val.z;
        tile[r * 33 + c4 + 3] = val.w;
        __syncthreads();
        float4 o;
        o.x = tile[(c4 + 0) * 33 + r];
        o.y = tile[(c4 + 1) * 33 + r];
        o.z = tile[(c4 + 2) * 33 + r];
        o.w = tile[(c4 + 3) * 33 + r];
        *(float4*)&dst[obase + (size_t)r * 128 + c4] = o;
    }
}

// ---------------------------------------------------------------------------
// Kernel 3: axial attention + 8->1 head projection, scalar-broadcast design.
// One line per block (line uniform from blockIdx => k/v row addresses are
// wave-uniform => scalar loads). 128 threads = the 128 outputs of the line.
// VER=0: line=row h, kr = K row (contiguous), out OH[sb][h][w].
// VER=1: line=col w, kr = KT row (contiguous), out OVT[sb][w][h] (coalesced).
// No max-subtract: |q*k| <~ 6 << exp2 range; matches ref to fp32 noise.
// grid 1024 x 128.
// ---------------------------------------------------------------------------
template <int VER>
__global__ __launch_bounds__(128) void attn_axial(
    const float* __restrict__ Q, const float* __restrict__ Ka,
    const float* __restrict__ Va, const float* __restrict__ wsel,
    float* __restrict__ o)
{
    const int t    = threadIdx.x;           // position along the line
    const int sb   = blockIdx.x >> 7;
    const int line = blockIdx.x & 127;      // uniform: enables s_load of kr/vr

    float w8[8];
#pragma unroll
    for (int i = 0; i < 8; ++i) w8[i] = wsel[i];

    float acc = 0.f;
    for (int head = 0; head < 8; ++head) {
        const size_t ph = (size_t)(sb * 8 + head) << 14;
        const float* kr = Ka + ph + ((size_t)line << 7);   // wave-uniform row
        const float* vr = Va + ph + ((size_t)line << 7);
        const float s = LOG2E * Q[ph + (VER ? ((size_t)t << 7) + line
                                            : ((size_t)line << 7) + t)];
        float num = 0.f, den = 0.f;
#pragma unroll 16
        for (int l = 0; l < 128; ++l) {
            const float e = exp2f(s * kr[l]);
            den += e;
            num = fmaf(e, vr[l], num);
        }
        acc = fmaf(w8[head], num / den, acc);
    }
    o[((size_t)sb << 14) + ((size_t)line << 7) + t] = acc;
}

// ---------------------------------------------------------------------------
// Kernel 4: bilinear border-clamped gather from ref (via phase mapping) +
// scatter to interleaved output. 2-way channel split. grid 1024 x 256.
// ---------------------------------------------------------------------------
__global__ __launch_bounds__(256) void warp_kernel(
    const float* __restrict__ ref, const float* __restrict__ ovt,
    const float* __restrict__ oh, float* __restrict__ out)
{
    const int g = blockIdx.x * 256 + threadIdx.x;   // 0..262143
    const int chalf = g >> 17;
    const int pid = g & (131072 - 1);
    const int sb  = pid >> 14;
    const int pix = pid & (PLANE - 1);
    const int h = pix >> 7, w = pix & 127;
    const int p = sb >> 1, b = sb & 1;
    const int dy = p & 1, dx = (p == 1) | (p == 2);

    // normalized-coord round trip cancels exactly:
    const float ix = (float)w + oh[pid];
    const float iy = (float)h + ovt[((size_t)sb << 14) + (w << 7) + h];

    const float x0f = floorf(ix), y0f = floorf(iy);
    const float wx = ix - x0f,    wy = iy - y0f;
    const int x0 = (int)x0f, y0 = (int)y0f;
    const int x0c = min(max(x0, 0), 127),     x1c = min(max(x0 + 1, 0), 127);
    const int y0c = min(max(y0, 0), 127),     y1c = min(max(y0 + 1, 0), 127);

    const float w00 = (1.f - wx) * (1.f - wy);
    const float w01 = wx * (1.f - wy);
    const float w10 = (1.f - wx) * wy;
    const float w11 = wx * wy;

    const int r0 = (2 * y0c + dy) * 256, r1 = (2 * y1c + dy) * 256;
    const int c0 = 2 * x0c + dx,         c1 = 2 * x1c + dx;
    const int o00 = r0 + c0, o01 = r0 + c1, o10 = r1 + c0, o11 = r1 + c1;
    const int dst = (2 * h + dy) * 256 + (2 * w + dx);

    const float* rp = ref + (size_t)b * 64 * 65536;
    float* op = out + (size_t)b * 64 * 65536;

    const int cbeg = chalf * 32;
#pragma unroll 4
    for (int c = 0; c < 32; ++c) {
        const size_t pl = (size_t)(cbeg + c) * 65536;
        const float v00 = rp[pl + o00], v01 = rp[pl + o01];
        const float v10 = rp[pl + o10], v11 = rp[pl + o11];
        op[pl + dst] = fmaf(w00, v00, fmaf(w01, v01, fmaf(w10, v10, w11 * v11)));
    }
}

// ---------------------------------------------------------------------------
extern "C" void kernel_launch(void* const* d_in, const int* in_sizes, int n_in,
                              void* d_out, int out_size, void* d_ws, size_t ws_size,
                              hipStream_t stream)
{
    const float* cur  = (const float*)d_in[0];
    const float* ref  = (const float*)d_in[1];
    const float* Wq   = (const float*)d_in[2];
    const float* Wk   = (const float*)d_in[3];
    const float* Wv   = (const float*)d_in[4];
    const float* Wver = (const float*)d_in[5];
    const float* Whor = (const float*)d_in[6];
    float* out = (float*)d_out;

    float* ws = (float*)d_ws;
    const size_t NQ = 8 * 8 * (size_t)PLANE;   // 1,048,576 floats
    float* Q   = ws;
    float* K   = Q  + NQ;
    float* V   = K  + NQ;
    float* KT  = V  + NQ;
    float* VT  = KT + NQ;
    float* OVT = VT + NQ;                      // [sb][w][h]
    float* OH  = OVT + 8 * (size_t)PLANE;      // [sb][h][w]

    qkv_kernel<<<1024, 256, 0, stream>>>(cur, ref, Wq, Wk, Wv, Q, K, V);
    transpose_kernel<<<1024, 256, 0, stream>>>(K, V, KT, VT);
    attn_axial<0><<<1024, 128, 0, stream>>>(Q, K,  V,  Whor, OH);   // horizontal
    attn_axial<1><<<1024, 128, 0, stream>>>(Q, KT, VT, Wver, OVT);  // vertical
    warp_kernel<<<1024, 256, 0, stream>>>(ref, OVT, OH, out);
}

// Round 3
// 189.451 us; speedup vs baseline: 1.3804x; 1.2513x over previous
//
#include <hip/hip_runtime.h>

// CrossWarpingModule: 4-phase pixel-unshuffle -> axial attention (8 heads, c=1)
// -> flow -> bilinear border grid_sample -> pixel-shuffle back.
// B=2, C=64, H=W=256; sub-images: 8 x [64][128][128].
//
// R3: attn redesigned for occupancy: block=(sb,line) x 1024 threads
// (head,t), k/v staged in LDS (broadcast reads), 4-wide accumulator ILP,
// raw v_exp_f32/v_rcp_f32. Q transposed alongside K,V so vertical attn is
// fully coalesced; both attn passes share one kernel body.

constexpr int PLANE = 16384;                 // 128*128
constexpr float LOG2E = 1.4426950408889634f;

// ---------------------------------------------------------------------------
// Kernel 1: q/k/v projection. Block = (b, Y, X-half): 128 contiguous X
// positions x 2 channel-groups. Reads stride-1 coalesced. grid 1024 x 256.
// ---------------------------------------------------------------------------
__global__ __launch_bounds__(256) void qkv_kernel(
    const float* __restrict__ cur, const float* __restrict__ ref,
    const float* __restrict__ Wq, const float* __restrict__ Wk,
    const float* __restrict__ Wv,
    float* __restrict__ Q, float* __restrict__ K, float* __restrict__ V)
{
    __shared__ float WT[64 * 24];     // WT[c][j]: j<8 Wq, <16 Wk, <24 Wv
    __shared__ float red[128 * 25];   // pad 25: conflict-free reduce
    const int tid = threadIdx.x;
    for (int i = tid; i < 64 * 24; i += 256) {
        int c = i / 24, j = i % 24;
        float val = (j < 8) ? Wq[j * 64 + c]
                  : (j < 16) ? Wk[(j - 8) * 64 + c]
                  : Wv[(j - 16) * 64 + c];
        WT[c * 24 + j] = val;
    }
    __syncthreads();

    const int bi = blockIdx.x;               // 0..1023
    const int b  = bi >> 9;                  // batch
    const int Y  = (bi >> 1) & 255;          // full-res row
    const int Xh = bi & 1;                   // X half
    const int cg = tid >> 7;                 // channel group 0/1
    const int xi = tid & 127;
    const int X  = Xh * 128 + xi;            // full-res col (contiguous per lane)

    const size_t base_in = (size_t)b * 64 * 65536 + (size_t)Y * 256 + X;
    const float* curp = cur + base_in;
    const float* refp = ref + base_in;

    float q[8], k[8], v[8];
#pragma unroll
    for (int i = 0; i < 8; ++i) { q[i] = 0.f; k[i] = 0.f; v[i] = 0.f; }

    const int c0 = cg * 32;
#pragma unroll 4
    for (int c = 0; c < 32; ++c) {
        float cu = curp[(size_t)(c0 + c) * 65536];
        float rf = refp[(size_t)(c0 + c) * 65536];
        const float* wr = &WT[(c0 + c) * 24];
#pragma unroll
        for (int i = 0; i < 8; ++i) {
            q[i] = fmaf(wr[i],      cu, q[i]);
            k[i] = fmaf(wr[8 + i],  rf, k[i]);
            v[i] = fmaf(wr[16 + i], rf, v[i]);
        }
    }

    if (cg) {
#pragma unroll
        for (int i = 0; i < 8; ++i) {
            red[xi * 25 + i]      = q[i];
            red[xi * 25 + 8 + i]  = k[i];
            red[xi * 25 + 16 + i] = v[i];
        }
    }
    __syncthreads();
    if (!cg) {
        const int dy = Y & 1, dx = X & 1;
        // (dy,dx)->phase: (0,0)=0 (1,1)=1 (0,1)=2 (1,0)=3
        const int p  = dy ? (dx ? 1 : 3) : (dx ? 2 : 0);
        const int sb = p * 2 + b;
        const int h = Y >> 1, w = X >> 1;
#pragma unroll
        for (int i = 0; i < 8; ++i) {
            const size_t o = ((size_t)(sb * 8 + i) << 14) + (h << 7) + w;
            Q[o] = q[i] + red[xi * 25 + i];
            K[o] = k[i] + red[xi * 25 + 8 + i];
            V[o] = v[i] + red[xi * 25 + 16 + i];
        }
    }
}

// ---------------------------------------------------------------------------
// Kernel 2: per-plane 128x128 transpose of Q,K,V -> QT,KT,VT. 32x32 LDS
// tiles, coalesced float4 on both sides. grid 1024 x 256.
// ---------------------------------------------------------------------------
__global__ __launch_bounds__(256) void transpose_kernel(
    const float* __restrict__ Q, const float* __restrict__ K,
    const float* __restrict__ V,
    float* __restrict__ QT, float* __restrict__ KT, float* __restrict__ VT)
{
    __shared__ float tile[32 * 33];
    const int bi = blockIdx.x;         // 0..1023
    const int plane = bi >> 4;         // (sb*8+head)
    const int ti = (bi >> 2) & 3, tj = bi & 3;
    const int t = threadIdx.x;
    const int r = t >> 3, c4 = (t & 7) * 4;     // 32 rows x 8 float4 cols
    const size_t pb = (size_t)plane << 14;
    const size_t ibase = pb + (size_t)(ti * 32) * 128 + tj * 32;
    const size_t obase = pb + (size_t)(tj * 32) * 128 + ti * 32;

    const float* srcs[3] = { Q, K, V };
    float* dsts[3] = { QT, KT, VT };
#pragma unroll
    for (int a = 0; a < 3; ++a) {
        const float* src = srcs[a];
        float* dst = dsts[a];
        const float4 val = *(const float4*)&src[ibase + (size_t)r * 128 + c4];
        if (a) __syncthreads();
        tile[r * 33 + c4 + 0] = val.x;
        tile[r * 33 + c4 + 1] = val.y;
        tile[r * 33 + c4 + 2] = val.z;
        tile[r * 33 + c4 + 3] = val.w;
        __syncthreads();
        float4 o;
        o.x = tile[(c4 + 0) * 33 + r];
        o.y = tile[(c4 + 1) * 33 + r];
        o.z = tile[(c4 + 2) * 33 + r];
        o.w = tile[(c4 + 3) * 33 + r];
        *(float4*)&dst[obase + (size_t)r * 128 + c4] = o;
    }
}

// ---------------------------------------------------------------------------
// Kernel 3: axial attention + 8->1 head projection.
// Block = (sb, line), 1024 threads = (head = tid>>7, t = tid&127).
// k (pre-scaled by log2e) and v staged in LDS; inner-loop addresses are
// wave-uniform (head is wave-uniform) -> pure broadcast ds_read_b128.
// 4 independent accumulator pairs break the FP dependency chains.
// Horizontal pass: (Q,K,V, Whor) -> OH[sb][h][w]   (line=h, t=w)
// Vertical pass:   (QT,KT,VT,Wver) -> OVT[sb][w][h] (line=w, t=h)
// No max-subtract: |q·k| <~ 6, far inside exp2 range (matches ref, fp32).
// grid 1024 x 1024.
// ---------------------------------------------------------------------------
__global__ __launch_bounds__(1024) void attn_axial(
    const float* __restrict__ Qa, const float* __restrict__ Ka,
    const float* __restrict__ Va, const float* __restrict__ wsel,
    float* __restrict__ o)
{
    __shared__ float kk[8 * 128];   // [head][l], pre-scaled by log2(e)
    __shared__ float vv[8 * 128];
    __shared__ float red[8 * 128];  // per-head softmax-weighted sums

    const int tid  = threadIdx.x;
    const int head = tid >> 7;
    const int t    = tid & 127;
    const int sb   = blockIdx.x >> 7;
    const int line = blockIdx.x & 127;

    const size_t ph = ((size_t)(sb * 8 + head)) << 14;
    const size_t row = ph + ((size_t)line << 7);
    kk[tid] = LOG2E * Ka[row + t];
    vv[tid] = Va[row + t];
    const float s = Qa[row + t];
    __syncthreads();

    const float4* k4 = (const float4*)&kk[head << 7];
    const float4* v4 = (const float4*)&vv[head << 7];
    float d0 = 0.f, d1 = 0.f, d2 = 0.f, d3 = 0.f;
    float n0 = 0.f, n1 = 0.f, n2 = 0.f, n3 = 0.f;
#pragma unroll 8
    for (int l = 0; l < 32; ++l) {
        const float4 kq = k4[l];
        const float4 vq = v4[l];
        const float e0 = __builtin_amdgcn_exp2f(s * kq.x);
        const float e1 = __builtin_amdgcn_exp2f(s * kq.y);
        const float e2 = __builtin_amdgcn_exp2f(s * kq.z);
        const float e3 = __builtin_amdgcn_exp2f(s * kq.w);
        d0 += e0; n0 = fmaf(e0, vq.x, n0);
        d1 += e1; n1 = fmaf(e1, vq.y, n1);
        d2 += e2; n2 = fmaf(e2, vq.z, n2);
        d3 += e3; n3 = fmaf(e3, vq.w, n3);
    }
    const float den = (d0 + d1) + (d2 + d3);
    const float num = (n0 + n1) + (n2 + n3);
    red[tid] = num * __builtin_amdgcn_rcpf(den);
    __syncthreads();

    if (tid < 128) {
        float acc = 0.f;
#pragma unroll
        for (int i = 0; i < 8; ++i)
            acc = fmaf(wsel[i], red[(i << 7) + tid], acc);
        o[((size_t)sb << 14) + ((size_t)line << 7) + tid] = acc;
    }
}

// ---------------------------------------------------------------------------
// Kernel 4: bilinear border-clamped gather from ref (via phase mapping) +
// scatter to interleaved output. 2-way channel split. grid 1024 x 256.
// ---------------------------------------------------------------------------
__global__ __launch_bounds__(256) void warp_kernel(
    const float* __restrict__ ref, const float* __restrict__ ovt,
    const float* __restrict__ oh, float* __restrict__ out)
{
    const int g = blockIdx.x * 256 + threadIdx.x;   // 0..262143
    const int chalf = g >> 17;
    const int pid = g & (131072 - 1);
    const int sb  = pid >> 14;
    const int pix = pid & (PLANE - 1);
    const int h = pix >> 7, w = pix & 127;
    const int p = sb >> 1, b = sb & 1;
    const int dy = p & 1, dx = (p == 1) | (p == 2);

    // normalized-coord round trip cancels exactly:
    const float ix = (float)w + oh[pid];
    const float iy = (float)h + ovt[((size_t)sb << 14) + (w << 7) + h];

    const float x0f = floorf(ix), y0f = floorf(iy);
    const float wx = ix - x0f,    wy = iy - y0f;
    const int x0 = (int)x0f, y0 = (int)y0f;
    const int x0c = min(max(x0, 0), 127),     x1c = min(max(x0 + 1, 0), 127);
    const int y0c = min(max(y0, 0), 127),     y1c = min(max(y0 + 1, 0), 127);

    const float w00 = (1.f - wx) * (1.f - wy);
    const float w01 = wx * (1.f - wy);
    const float w10 = (1.f - wx) * wy;
    const float w11 = wx * wy;

    const int r0 = (2 * y0c + dy) * 256, r1 = (2 * y1c + dy) * 256;
    const int c0 = 2 * x0c + dx,         c1 = 2 * x1c + dx;
    const int o00 = r0 + c0, o01 = r0 + c1, o10 = r1 + c0, o11 = r1 + c1;
    const int dst = (2 * h + dy) * 256 + (2 * w + dx);

    const float* rp = ref + (size_t)b * 64 * 65536;
    float* op = out + (size_t)b * 64 * 65536;

    const int cbeg = chalf * 32;
#pragma unroll 4
    for (int c = 0; c < 32; ++c) {
        const size_t pl = (size_t)(cbeg + c) * 65536;
        const float v00 = rp[pl + o00], v01 = rp[pl + o01];
        const float v10 = rp[pl + o10], v11 = rp[pl + o11];
        op[pl + dst] = fmaf(w00, v00, fmaf(w01, v01, fmaf(w10, v10, w11 * v11)));
    }
}

// ---------------------------------------------------------------------------
extern "C" void kernel_launch(void* const* d_in, const int* in_sizes, int n_in,
                              void* d_out, int out_size, void* d_ws, size_t ws_size,
                              hipStream_t stream)
{
    const float* cur  = (const float*)d_in[0];
    const float* ref  = (const float*)d_in[1];
    const float* Wq   = (const float*)d_in[2];
    const float* Wk   = (const float*)d_in[3];
    const float* Wv   = (const float*)d_in[4];
    const float* Wver = (const float*)d_in[5];
    const float* Whor = (const float*)d_in[6];
    float* out = (float*)d_out;

    float* ws = (float*)d_ws;
    const size_t NQ = 8 * 8 * (size_t)PLANE;   // 1,048,576 floats
    float* Q   = ws;
    float* K   = Q  + NQ;
    float* V   = K  + NQ;
    float* QT  = V  + NQ;
    float* KT  = QT + NQ;
    float* VT  = KT + NQ;
    float* OVT = VT + NQ;                      // [sb][w][h]
    float* OH  = OVT + 8 * (size_t)PLANE;      // [sb][h][w]

    qkv_kernel<<<1024, 256, 0, stream>>>(cur, ref, Wq, Wk, Wv, Q, K, V);
    transpose_kernel<<<1024, 256, 0, stream>>>(Q, K, V, QT, KT, VT);
    attn_axial<<<1024, 1024, 0, stream>>>(Q,  K,  V,  Whor, OH);    // horizontal
    attn_axial<<<1024, 1024, 0, stream>>>(QT, KT, VT, Wver, OVT);   // vertical
    warp_kernel<<<1024, 256, 0, stream>>>(ref, OVT, OH, out);
}